// Round 8
// baseline (217.752 us; speedup 1.0000x reference)
//
#include <hip/hip_runtime.h>
#include <math.h>

#define BATCH 256
#define FB    64
#define NCOL  147456              // 128*128*3*3
#define TPB   256
#define MT    32                  // batch rows per block
#define NTB   512                 // cols per block
#define NXB   (NCOL / NTB)        // 288 column blocks
#define NBG   (BATCH / MT)        // 8 batch groups
#define PTS   68                  // LDS probs row stride: 272B, 16B-aligned for
                                  // b128 reads; 4-bank shift/row -> <=8-way
                                  // conflict on the 8 one-off fragment reads

// MFMA fragment types (guide-verified short8 signature for gfx950 bf16 MFMA).
typedef __attribute__((ext_vector_type(8))) short bf16x8;
typedef __attribute__((ext_vector_type(4))) float f32x4;

// hi = truncate-to-bf16 (top 16 bits); lo = exact fp32 residual, re-truncated.
// out = Ph*Wh + Ph*Wl + Pl*Wh reproduces fp32 to ~2^-16 rel (dropped Pl*Wl).
__device__ __forceinline__ short bhi(float x) {
    return (short)(__float_as_uint(x) >> 16);
}
__device__ __forceinline__ float fhi(float x) {
    return __uint_as_float(__float_as_uint(x) & 0xffff0000u);
}

// Fused softmax + split-bf16 MFMA GEMM: out[b][n] = sum_f softmax(X)[b][f]*W[f][n].
// Block: 4 waves, 32 rows x 512 cols. Wave w: rows {0..31}, cols w*128..+128
// = 2 row-tiles x 8 col-tiles of 16x16. Fragment layout (m89/m91-verified):
//   A: row=lane&15, k=(lane>>4)*8+i   B: col=lane&15, k=(lane>>4)*8+i
//   C/D: col=lane&15, row=(lane>>4)*4+reg
__global__ __launch_bounds__(TPB, 2) void bank_gemm_mfma_fused(
        const float* __restrict__ W, const float* __restrict__ X,
        float* __restrict__ out) {
    __shared__ float pt[MT * PTS];    // 8.5 KB probs tile

    const int tid  = threadIdx.x;
    const int wv   = tid >> 6;        // wave 0..3
    const int lane = tid & 63;
    const int kg   = lane >> 4;       // k-group 0..3
    const int lr   = lane & 15;

    // XCD-chunked swizzle (halves FETCH_SIZE): the 8 batch-group partners of
    // one column block run consecutively on one XCD -> W slice L2-resident.
    const int wg   = blockIdx.y * gridDim.x + blockIdx.x;  // 0..2303
    const int xcd  = wg & 7;
    const int slot = wg >> 3;                              // 0..287
    const int bx   = xcd * (NXB / 8) + (slot >> 3);        // column block 0..287
    const int bg   = slot & (NBG - 1);                     // batch group 0..7

    const int row0 = bg * MT;
    const int col0 = bx * NTB + wv * 128;

    // ---- Fused softmax prologue: wave wv owns local rows wv*8..wv*8+7,
    // lane == filter index (FB == 64). Redundant across the 288 column-blocks
    // of this bg, but only 8 KB of L2-hit reads per block. Saves the separate
    // softmax dispatch + inter-kernel gap (~4-6 us).
#pragma unroll
    for (int rr = 0; rr < MT / 4; ++rr) {
        const int r = wv * (MT / 4) + rr;
        float v = X[(row0 + r) * FB + lane];
        float m = v;
#pragma unroll
        for (int o = 32; o > 0; o >>= 1) m = fmaxf(m, __shfl_xor(m, o));
        float e = __expf(v - m);
        float s = e;
#pragma unroll
        for (int o = 32; o > 0; o >>= 1) s += __shfl_xor(s, o);
        pt[r * PTS + lane] = e / s;   // stride-1 write: conflict-free
    }
    __syncthreads();

    // ---- A fragments from LDS: probs hi/lo, [row-tile][K-step].
    bf16x8 pah[2][2], pal[2][2];
#pragma unroll
    for (int rt = 0; rt < 2; ++rt) {
#pragma unroll
        for (int s = 0; s < 2; ++s) {
            const float* pr = &pt[(rt * 16 + lr) * PTS + s * 32 + kg * 8];
            float av[8];
            *(f32x4*)&av[0] = *(const f32x4*)pr;
            *(f32x4*)&av[4] = *(const f32x4*)(pr + 4);
#pragma unroll
            for (int i = 0; i < 8; ++i) {
                const float xx = av[i];
                pah[rt][s][i] = bhi(xx);
                pal[rt][s][i] = bhi(xx - fhi(xx));
            }
        }
    }

    f32x4 acc[2][8];
#pragma unroll
    for (int rt = 0; rt < 2; ++rt)
#pragma unroll
        for (int t = 0; t < 8; ++t)
            acc[rt][t] = (f32x4){0.f, 0.f, 0.f, 0.f};

    // ---- Main loop over this wave's 8 col-tiles. B gathered straight from
    // W (fp32) in L2: lane reads W[s*32+kg*8+i][col], 16-lane groups give
    // 64B-coalesced segments. Fully unrolled (static acc indices, rule #20).
    const float* wbase = W + (kg * 8) * NCOL + col0 + lr;
#pragma unroll
    for (int t = 0; t < 8; ++t) {
        const float* wp = wbase + t * 16;
        float wv0[8], wv1[8];
#pragma unroll
        for (int i = 0; i < 8; ++i) {
            wv0[i] = wp[i * NCOL];            // K-step 0: f = kg*8 + i
            wv1[i] = wp[(32 + i) * NCOL];     // K-step 1: f = 32 + kg*8 + i
        }
        bf16x8 wh0, wl0, wh1, wl1;
#pragma unroll
        for (int i = 0; i < 8; ++i) {
            wh0[i] = bhi(wv0[i]); wl0[i] = bhi(wv0[i] - fhi(wv0[i]));
            wh1[i] = bhi(wv1[i]); wl1[i] = bhi(wv1[i] - fhi(wv1[i]));
        }
#pragma unroll
        for (int rt = 0; rt < 2; ++rt) {
            f32x4 c = acc[rt][t];
            c = __builtin_amdgcn_mfma_f32_16x16x32_bf16(pah[rt][0], wh0, c, 0, 0, 0);
            c = __builtin_amdgcn_mfma_f32_16x16x32_bf16(pah[rt][1], wh1, c, 0, 0, 0);
            c = __builtin_amdgcn_mfma_f32_16x16x32_bf16(pah[rt][0], wl0, c, 0, 0, 0);
            c = __builtin_amdgcn_mfma_f32_16x16x32_bf16(pah[rt][1], wl1, c, 0, 0, 0);
            c = __builtin_amdgcn_mfma_f32_16x16x32_bf16(pal[rt][0], wh0, c, 0, 0, 0);
            c = __builtin_amdgcn_mfma_f32_16x16x32_bf16(pal[rt][1], wh1, c, 0, 0, 0);
            acc[rt][t] = c;
        }
    }

    // ---- Epilogue: non-temporal scalar stores (output is write-once, never
    // re-read -> don't evict the per-XCD W slice from L2). Per store instr,
    // lanes 0-15 write 64B contiguous; 4 segments/instr, fully coalesced.
#pragma unroll
    for (int rt = 0; rt < 2; ++rt)
#pragma unroll
        for (int t = 0; t < 8; ++t)
#pragma unroll
            for (int r = 0; r < 4; ++r)
                __builtin_nontemporal_store(
                    acc[rt][t][r],
                    &out[(size_t)(row0 + rt * 16 + kg * 4 + r) * NCOL
                         + col0 + t * 16 + lr]);
}

extern "C" void kernel_launch(void* const* d_in, const int* in_sizes, int n_in,
                              void* d_out, int out_size, void* d_ws, size_t ws_size,
                              hipStream_t stream) {
    const float* bank   = (const float*)d_in[0];   // (256, 64)
    const float* weight = (const float*)d_in[1];   // (64, 128,128,3,3)
    float* out   = (float*)d_out;                  // (256, 147456)
    (void)d_ws; (void)ws_size;                     // no workspace needed

    dim3 grid(NXB, NBG);   // (288, 8) = 2304 blocks
    bank_gemm_mfma_fused<<<grid, TPB, 0, stream>>>(weight, bank, out);
}

// Round 9
// 204.957 us; speedup vs baseline: 1.0624x; 1.0624x over previous
//
#include <hip/hip_runtime.h>
#include <math.h>

#define BATCH 256
#define FB    64
#define NCOL  147456              // 128*128*3*3
#define TPB   256
#define MT    32                  // batch rows per block
#define NTB   512                 // cols per block
#define NXB   (NCOL / NTB)        // 288 column blocks
#define NBG   (BATCH / MT)        // 8 batch groups

// MFMA fragment types (guide-verified short8 signature for gfx950 bf16 MFMA).
typedef __attribute__((ext_vector_type(8))) short bf16x8;
typedef __attribute__((ext_vector_type(4))) float f32x4;

// hi = truncate-to-bf16 (top 16 bits); lo = exact fp32 residual, re-truncated.
// out = Ph*Wh + Ph*Wl + Pl*Wh reproduces fp32 to ~2^-16 rel (dropped Pl*Wl).
__device__ __forceinline__ short bhi(float x) {
    return (short)(__float_as_uint(x) >> 16);
}
__device__ __forceinline__ float fhi(float x) {
    return __uint_as_float(__float_as_uint(x) & 0xffff0000u);
}

// One wave (64 lanes == FB) per batch row -> row-major probs P[b][f].
__global__ void softmax_rows(const float* __restrict__ x, float* __restrict__ p) {
    const int b = blockIdx.x;
    const int lane = threadIdx.x;
    float v = x[b * FB + lane];
    float m = v;
#pragma unroll
    for (int o = 32; o > 0; o >>= 1) m = fmaxf(m, __shfl_xor(m, o));
    float e = __expf(v - m);
    float s = e;
#pragma unroll
    for (int o = 32; o > 0; o >>= 1) s += __shfl_xor(s, o);
    p[b * FB + lane] = e / s;
}

// Split-bf16 MFMA GEMM: out[b][n] = sum_f P[b][f] * W[f][n], K=64.
// Block: 4 waves, 32 rows x 512 cols. Wave w: rows {0..31}, cols w*128..+128
// = 2 row-tiles x 8 col-tiles of 16x16. 12 MFMA per col-tile (3 products x
// 2 K-steps x 2 row-tiles shared-B). Fragment layout (m89/m91-verified):
//   A: row=lane&15, k=(lane>>4)*8+i   B: col=lane&15, k=(lane>>4)*8+i
//   C/D: col=lane&15, row=(lane>>4)*4+reg
// NOTE (round-8 lesson): plain stores, NOT __builtin_nontemporal_store —
// nt scalar stores defeat L2 write-combining (+23 MB HBM write amplification).
__global__ __launch_bounds__(TPB, 2) void bank_gemm_mfma(
        const float* __restrict__ W, const float* __restrict__ P,
        float* __restrict__ out) {
    const int tid  = threadIdx.x;
    const int wv   = tid >> 6;        // wave 0..3
    const int lane = tid & 63;
    const int kg   = lane >> 4;       // k-group 0..3
    const int lr   = lane & 15;

    // XCD-chunked swizzle (halves FETCH_SIZE): the 8 batch-group partners of
    // one column block run consecutively on one XCD -> W slice L2-resident.
    const int wg   = blockIdx.y * gridDim.x + blockIdx.x;  // 0..2303
    const int xcd  = wg & 7;
    const int slot = wg >> 3;                              // 0..287
    const int bx   = xcd * (NXB / 8) + (slot >> 3);        // column block 0..287
    const int bg   = slot & (NBG - 1);                     // batch group 0..7

    const int row0 = bg * MT;
    const int col0 = bx * NTB + wv * 128;

    // ---- A fragments: probs hi/lo, [row-tile][K-step]. 8 consecutive f per
    // lane -> two aligned float4 loads per fragment.
    bf16x8 pah[2][2], pal[2][2];
#pragma unroll
    for (int rt = 0; rt < 2; ++rt) {
#pragma unroll
        for (int s = 0; s < 2; ++s) {
            const float* pr = P + (row0 + rt * 16 + lr) * FB + s * 32 + kg * 8;
            float av[8];
            *(f32x4*)&av[0] = *(const f32x4*)pr;
            *(f32x4*)&av[4] = *(const f32x4*)(pr + 4);
#pragma unroll
            for (int i = 0; i < 8; ++i) {
                const float xx = av[i];
                pah[rt][s][i] = bhi(xx);
                pal[rt][s][i] = bhi(xx - fhi(xx));
            }
        }
    }

    f32x4 acc[2][8];
#pragma unroll
    for (int rt = 0; rt < 2; ++rt)
#pragma unroll
        for (int t = 0; t < 8; ++t)
            acc[rt][t] = (f32x4){0.f, 0.f, 0.f, 0.f};

    // ---- Main loop over this wave's 8 col-tiles. B gathered straight from
    // W (fp32) in L2: lane reads W[s*32+kg*8+i][col], 16-lane groups give
    // 64B-coalesced segments. Fully unrolled (static acc indices, rule #20).
    const float* wbase = W + (kg * 8) * NCOL + col0 + lr;
#pragma unroll
    for (int t = 0; t < 8; ++t) {
        const float* wp = wbase + t * 16;
        float wv0[8], wv1[8];
#pragma unroll
        for (int i = 0; i < 8; ++i) {
            wv0[i] = wp[i * NCOL];            // K-step 0: f = kg*8 + i
            wv1[i] = wp[(32 + i) * NCOL];     // K-step 1: f = 32 + kg*8 + i
        }
        bf16x8 wh0, wl0, wh1, wl1;
#pragma unroll
        for (int i = 0; i < 8; ++i) {
            wh0[i] = bhi(wv0[i]); wl0[i] = bhi(wv0[i] - fhi(wv0[i]));
            wh1[i] = bhi(wv1[i]); wl1[i] = bhi(wv1[i] - fhi(wv1[i]));
        }
#pragma unroll
        for (int rt = 0; rt < 2; ++rt) {
            f32x4 c = acc[rt][t];
            c = __builtin_amdgcn_mfma_f32_16x16x32_bf16(pah[rt][0], wh0, c, 0, 0, 0);
            c = __builtin_amdgcn_mfma_f32_16x16x32_bf16(pah[rt][1], wh1, c, 0, 0, 0);
            c = __builtin_amdgcn_mfma_f32_16x16x32_bf16(pah[rt][0], wl0, c, 0, 0, 0);
            c = __builtin_amdgcn_mfma_f32_16x16x32_bf16(pah[rt][1], wl1, c, 0, 0, 0);
            c = __builtin_amdgcn_mfma_f32_16x16x32_bf16(pal[rt][0], wh0, c, 0, 0, 0);
            c = __builtin_amdgcn_mfma_f32_16x16x32_bf16(pal[rt][1], wh1, c, 0, 0, 0);
            acc[rt][t] = c;
        }
    }

    // ---- Epilogue: C/D fragment stores. Per store instr, lanes 0-15 write
    // 64B contiguous (rows differ per kg group); adjacent col-tiles merge in L2.
#pragma unroll
    for (int rt = 0; rt < 2; ++rt)
#pragma unroll
        for (int t = 0; t < 8; ++t)
#pragma unroll
            for (int r = 0; r < 4; ++r)
                out[(size_t)(row0 + rt * 16 + kg * 4 + r) * NCOL
                    + col0 + t * 16 + lr] = acc[rt][t][r];
}

extern "C" void kernel_launch(void* const* d_in, const int* in_sizes, int n_in,
                              void* d_out, int out_size, void* d_ws, size_t ws_size,
                              hipStream_t stream) {
    const float* bank   = (const float*)d_in[0];   // (256, 64)
    const float* weight = (const float*)d_in[1];   // (64, 128,128,3,3)
    float* out   = (float*)d_out;                  // (256, 147456)
    float* probs = (float*)d_ws;                   // 256*64 fp32 = 64 KB

    softmax_rows<<<BATCH, FB, 0, stream>>>(bank, probs);

    dim3 grid(NXB, NBG);   // (288, 8) = 2304 blocks
    bank_gemm_mfma<<<grid, TPB, 0, stream>>>(weight, probs, out);
}